// Round 1
// baseline (274.233 us; speedup 1.0000x reference)
//
#include <hip/hip_runtime.h>
#include <stdint.h>

#define DIM 1024
#define GROUP 128
#define NGROUP (DIM / GROUP)   // 8

// out[t][d] = sign_ste(W[ids[t]][d]) * max(scales[ids[t]][d/GROUP], 1e-8)
// sign_ste(x): +1 if x > 0 or x == +/-0, -1 if x < 0.
// scales are clamped to >= 1e-8 (positive), so the result's bits are just
// bits(s) with the weight's sign bit OR'd in (suppressed when w == 0).
__global__ __launch_bounds__(256) void literati_embed_kernel(
    const int*   __restrict__ ids,
    const float* __restrict__ weight,
    const float* __restrict__ scales,
    float*       __restrict__ out,
    int n_tokens)
{
    const int token = blockIdx.x;
    if (token >= n_tokens) return;

    const int tid = threadIdx.x;          // 0..255, each lane = 4 floats
    const int row = ids[token];           // same addr for whole block -> broadcast

    const float4* wrow = reinterpret_cast<const float4*>(weight + (size_t)row * DIM);
    float4*       orow = reinterpret_cast<float4*>(out + (size_t)token * DIM);

    // elements [4*tid .. 4*tid+3] all fall in group (4*tid)/GROUP = tid>>5
    float s = scales[row * NGROUP + (tid >> 5)];
    s = fmaxf(s, 1e-8f);
    const uint32_t sbits = __float_as_uint(s);

    const float4 w = wrow[tid];

    float4 r;
    {
        uint32_t b = sbits | ((w.x != 0.0f) ? (__float_as_uint(w.x) & 0x80000000u) : 0u);
        r.x = __uint_as_float(b);
    }
    {
        uint32_t b = sbits | ((w.y != 0.0f) ? (__float_as_uint(w.y) & 0x80000000u) : 0u);
        r.y = __uint_as_float(b);
    }
    {
        uint32_t b = sbits | ((w.z != 0.0f) ? (__float_as_uint(w.z) & 0x80000000u) : 0u);
        r.z = __uint_as_float(b);
    }
    {
        uint32_t b = sbits | ((w.w != 0.0f) ? (__float_as_uint(w.w) & 0x80000000u) : 0u);
        r.w = __uint_as_float(b);
    }

    orow[tid] = r;
}

extern "C" void kernel_launch(void* const* d_in, const int* in_sizes, int n_in,
                              void* d_out, int out_size, void* d_ws, size_t ws_size,
                              hipStream_t stream) {
    const int*   ids    = (const int*)d_in[0];    // [8, 2048] int32
    const float* weight = (const float*)d_in[1];  // [50257, 1024] f32
    const float* scales = (const float*)d_in[2];  // [50257, 8] f32
    float*       out    = (float*)d_out;          // [8, 2048, 1024] f32

    const int n_tokens = in_sizes[0];             // 16384

    literati_embed_kernel<<<n_tokens, 256, 0, stream>>>(ids, weight, scales, out, n_tokens);
}

// Round 4
// 273.357 us; speedup vs baseline: 1.0032x; 1.0032x over previous
//
#include <hip/hip_runtime.h>
#include <stdint.h>

#define DIM 1024
#define GROUP 128
#define NGROUP (DIM / GROUP)   // 8
#define TPB 8                  // tokens per batch per block

typedef float  fx4 __attribute__((ext_vector_type(4)));   // native clang vector:
                                                          // valid for nontemporal builtins

// out[t][d] = sign_ste(W[ids[t]][d]) * max(scales[ids[t]][d/GROUP], 1e-8)
// sign_ste(x): +1 for x>0 or x==+/-0, -1 for x<0. Since max(scale,1e-8) > 0,
// result bits = bits(clamped scale) | signbit(w) (suppressed when w == +/-0).
//
// Structure: 2048 blocks x 256 threads. Each block takes TPB=8 consecutive
// tokens per grid-stride step. The 8 ids loads are wave-uniform (s_load),
// hoisted ahead; then 8 independent gathered float4 row loads + scale loads
// are all in flight before any consumer -> 8-deep memory-level parallelism
// per thread instead of 1 (R1 was a serial id->row->store chain per tiny
// block, latency-bound at 467 GB/s effective).
__global__ __launch_bounds__(256) void literati_embed_kernel(
    const int*   __restrict__ ids,
    const float* __restrict__ weight,
    const float* __restrict__ scales,
    float*       __restrict__ out,
    int n_tokens)
{
    const int tid  = threadIdx.x;      // 0..255; thread covers floats [4*tid..4*tid+3]
    const int gidx = tid >> 5;         // scale group index for this thread's float4
    const int step = gridDim.x * TPB;

    for (int base = blockIdx.x * TPB; base < n_tokens; base += step) {
        // 1) hoist ids (uniform address -> scalar loads, issued back-to-back)
        int rows[TPB];
#pragma unroll
        for (int i = 0; i < TPB; ++i) {
            int t = base + i;
            rows[i] = ids[t < n_tokens ? t : (n_tokens - 1)];
        }

        // 2) issue all gathered loads (independent -> 8-deep MLP)
        fx4   w[TPB];
        float s[TPB];
#pragma unroll
        for (int i = 0; i < TPB; ++i) {
            w[i] = reinterpret_cast<const fx4*>(weight + (size_t)rows[i] * DIM)[tid];
            s[i] = scales[rows[i] * NGROUP + gidx];
        }

        // 3) combine + nontemporal store (output is write-once; keep it out of
        //    L2 so gathered weight rows stay cached)
#pragma unroll
        for (int i = 0; i < TPB; ++i) {
            int t = base + i;
            if (t < n_tokens) {
                const uint32_t sb = __float_as_uint(fmaxf(s[i], 1e-8f));
                fx4 r;
#pragma unroll
                for (int j = 0; j < 4; ++j) {
                    float wj = w[i][j];
                    uint32_t b = sb | ((wj != 0.0f) ? (__float_as_uint(wj) & 0x80000000u) : 0u);
                    r[j] = __uint_as_float(b);
                }
                fx4* op = reinterpret_cast<fx4*>(out + (size_t)t * DIM) + tid;
                __builtin_nontemporal_store(r, op);
            }
        }
    }
}

extern "C" void kernel_launch(void* const* d_in, const int* in_sizes, int n_in,
                              void* d_out, int out_size, void* d_ws, size_t ws_size,
                              hipStream_t stream) {
    const int*   ids    = (const int*)d_in[0];    // [8, 2048] int32
    const float* weight = (const float*)d_in[1];  // [50257, 1024] f32
    const float* scales = (const float*)d_in[2];  // [50257, 8] f32
    float*       out    = (float*)d_out;          // [8, 2048, 1024] f32

    const int n_tokens = in_sizes[0];             // 16384

    // ceil(n_tokens / TPB) blocks -> all resident (256-thread blocks,
    // ~8 blocks/CU x 256 CUs = 2048)
    const int grid = (n_tokens + TPB - 1) / TPB;

    literati_embed_kernel<<<grid, 256, 0, stream>>>(ids, weight, scales, out, n_tokens);
}